// Round 4
// baseline (114.435 us; speedup 1.0000x reference)
//
#include <hip/hip_runtime.h>
#include <hip/hip_bf16.h>

using short8 = __attribute__((ext_vector_type(8))) short;
using f32x4  = __attribute__((ext_vector_type(4))) float;

#define HD 128
#define NN 256

static __device__ __forceinline__ unsigned short us(float v) {
    union { __hip_bfloat16 b; unsigned short s; } c; c.b = __float2bfloat16(v); return c.s;
}
static __device__ __forceinline__ unsigned int pk2(float a, float b) {
    return (unsigned int)us(a) | ((unsigned int)us(b) << 16);
}
// fast silu: rcp-based division (bf16-grade accuracy is plenty here)
static __device__ __forceinline__ float fsilu(float v) {
    return __fdividef(v, 1.f + __expf(-v));
}
static __device__ __forceinline__ float ftanh(float v) {
    return 1.f - __fdividef(2.f, __expf(2.f * v) + 1.f);
}
// XOR-swizzled LDS byte addr for [rows][128] bf16 tile (256B row stride)
static __device__ __forceinline__ int swz(int row, int kbyte) { return row * 256 + (kbyte ^ ((row & 7) << 4)); }
// XOR-swizzled LDS byte addr for [rows][256] bf16 tile (512B row stride)
static __device__ __forceinline__ int swz512(int row, int kbyte) { return row * 512 + (kbyte ^ ((row & 7) << 4)); }

// ---- fused prep: weight packing (5 matrices) + mask compaction ----
// pack layout (Ncols-col matrix): pk[((k>>3)*Ncols + n)*8 + (k&7)] = bf16(w[k][n])
__global__ __launch_bounds__(256) void prep_all(
    const float* __restrict__ we2, const float* __restrict__ wc1,
    const float* __restrict__ wn1, const float* __restrict__ wn2,
    const float* __restrict__ we1, const int* __restrict__ mask,
    unsigned short* __restrict__ we2pk, unsigned short* __restrict__ wc1pk,
    unsigned short* __restrict__ wn1pk, unsigned short* __restrict__ wn2pk,
    unsigned short* __restrict__ we1pk,
    int* __restrict__ idxB, int* __restrict__ cntB)
{
    const int blk = blockIdx.x;
    const int t = threadIdx.x;
    if (blk < 448) {
        const int idx = blk * 256 + t;          // 0..114687
        if (idx < 81920) {
            const float* src; unsigned short* dst; int local;
            if (idx < 16384)      { src = we2; dst = we2pk; local = idx;         }
            else if (idx < 32768) { src = wc1; dst = wc1pk; local = idx - 16384; }
            else if (idx < 65536) { src = wn1; dst = wn1pk; local = idx - 32768; }
            else                  { src = wn2; dst = wn2pk; local = idx - 65536; }
            const int k = local >> 7, n = local & 127;
            dst[((k >> 3) * 128 + n) * 8 + (k & 7)] = us(src[local]);
        } else {
            // we1: build W[k][n] = (n<128) ? we1[k][n] : we1[128+k][n-128]
            // (column-concat of we1 rows 0:128 and 128:256 — NOT contiguous in src)
            const int local = idx - 81920;      // 0..32767
            const int k = local >> 8, n = local & 255;
            const int srci = (n < HD) ? (k * HD + n) : ((HD + k) * HD + (n - HD));
            we1pk[((k >> 3) * 256 + n) * 8 + (k & 7)] = us(we1[srci]);
        }
    } else {
        const int b = blk - 448;                // 0..7
        const int lane = t & 63, wv = t >> 6;
        const int m = mask[b * NN + t];
        const unsigned long long bal = __ballot(m != 0);
        const int pos = __popcll(bal & ((1ULL << lane) - 1ULL));
        __shared__ int wc[4];
        if (lane == 0) wc[wv] = __popcll(bal);
        __syncthreads();
        int base = 0;
        for (int w = 0; w < wv; ++w) base += wc[w];
        if (m) idxB[b * NN + base + pos] = t;
        if (t == 0) cntB[b] = wc[0] + wc[1] + wc[2] + wc[3];
    }
}

// ---- prep: Apre/Bpre = h @ W (256 cols) via MFMA (16 rows/block) ----
__global__ __launch_bounds__(256) void prep_node_mfma(
    const float* __restrict__ h, const unsigned short* __restrict__ we1pk,
    const float* __restrict__ be1,
    float* __restrict__ Apre, float* __restrict__ Bpre)
{
    const int r0 = blockIdx.x * 16;
    const int tid = threadIdx.x;
    const int wv = tid >> 6, lane = tid & 63, g = lane >> 4, cl = lane & 15;
    __shared__ __align__(16) unsigned short t1[16 * HD];
    {
        const int row = tid >> 4, k0 = (tid & 15) * 8;
        const float4 a0 = *(const float4*)(h + (size_t)(r0 + row) * HD + k0);
        const float4 a1 = *(const float4*)(h + (size_t)(r0 + row) * HD + k0 + 4);
        uint4 o;
        o.x = pk2(a0.x, a0.y); o.y = pk2(a0.z, a0.w);
        o.z = pk2(a1.x, a1.y); o.w = pk2(a1.z, a1.w);
        *(uint4*)((char*)t1 + swz(row, 2 * k0)) = o;
    }
    __syncthreads();
    const f32x4 zero4 = {0.f, 0.f, 0.f, 0.f};
    f32x4 acc[4] = {zero4, zero4, zero4, zero4};
    #pragma unroll
    for (int ks = 0; ks < 4; ++ks) {
        const short8 a = *(const short8*)((char*)t1 + swz(cl, ks * 64 + g * 16));
        #pragma unroll
        for (int nt = 0; nt < 4; ++nt) {
            const int col = wv * 64 + nt * 16 + cl;
            const short8 bb = *(const short8*)(we1pk + ((ks * 4 + g) * 256 + col) * 8);
            acc[nt] = __builtin_amdgcn_mfma_f32_16x16x32_bf16(a, bb, acc[nt], 0, 0, 0);
        }
    }
    #pragma unroll
    for (int nt = 0; nt < 4; ++nt) {
        const int col = wv * 64 + nt * 16 + cl;
        const float bias = (col < HD) ? be1[col] : 0.f;
        #pragma unroll
        for (int r = 0; r < 4; ++r) {
            const int row = r0 + g * 4 + r;
            const float v = acc[nt][r] + bias;
            if (col < HD) Apre[(size_t)row * HD + col] = v;
            else          Bpre[(size_t)row * HD + (col - HD)] = v;
        }
    }
}

// ---- main: one block (512 thr, 8 waves) per (b,i) — edge MLPs + coord + agg ----
__global__ __launch_bounds__(512) void egcl_main(
    const float* __restrict__ x, const int* __restrict__ mask,
    const float* __restrict__ we1, const float* __restrict__ be2,
    const float* __restrict__ bc1, const float* __restrict__ wc2,
    const float* __restrict__ Apre, const float* __restrict__ Bpre,
    const unsigned short* __restrict__ we2pk, const unsigned short* __restrict__ wc1pk,
    const int* __restrict__ idxB, const int* __restrict__ cntB,
    float* __restrict__ aggws, float* __restrict__ xout)
{
    const int blk = blockIdx.x;
    const int b = blk >> 8, i = blk & 255;
    const int rowb = b * NN + i;
    const int tid = threadIdx.x;
    const int wv = tid >> 6, lane = tid & 63, g = lane >> 4, cl = lane & 15;

    __shared__ __align__(16) unsigned short t1[64 * HD];
    __shared__ __align__(16) unsigned short t2[64 * HD];
    __shared__ int idx_s[NN];
    __shared__ __align__(16) float Ai_s[HD], wlast_s[HD];
    __shared__ float be2_s[HD], bc1_s[HD], wc2_s[HD];
    __shared__ float sws[8][64];

    const int cnt = cntB[b];
    if (tid < NN) idx_s[tid] = (tid < cnt) ? idxB[b * NN + tid] : 0;
    else if (tid < NN + HD) { const int c = tid - NN; Ai_s[c] = Apre[(size_t)rowb * HD + c]; }
    else { const int c = tid - NN - HD; wlast_s[c] = we1[2 * HD * HD + c]; }
    if (tid < HD) be2_s[tid] = be2[tid];
    else if (tid < 2 * HD) bc1_s[tid - HD] = bc1[tid - HD];
    else if (tid < 3 * HD) wc2_s[tid - 2 * HD] = wc2[tid - 2 * HD];

    // per-wave weight fragments: wave owns cols [wv*16, wv*16+16)
    short8 bw2[4], bwc[4];
    #pragma unroll
    for (int ks = 0; ks < 4; ++ks) {
        const int off = ((ks * 4 + g) * HD + wv * 16 + cl) * 8;
        bw2[ks] = *(const short8*)(we2pk + off);
        bwc[ks] = *(const short8*)(wc1pk + off);
    }

    const float xi0 = x[rowb * 3 + 0];
    const float xi1 = x[rowb * 3 + 1];
    const float xi2 = x[rowb * 3 + 2];
    const bool act = (mask[rowb] != 0);
    float agg0 = 0.f, cdx = 0.f, cdy = 0.f, cdz = 0.f;
    const f32x4 zero4 = {0.f, 0.f, 0.f, 0.f};
    const int nch = act ? ((cnt + 63) >> 6) : 0;
    const int mycol = wv * 16 + cl;

    __syncthreads();   // staging visible

    // ---- phase A: m1 = silu(A_i + B_j + d2*wlast) -> bf16 t1 (swizzled) ----
    #define PHASE_A(JC) do { \
        const int jl = tid >> 3; \
        const int h0 = (tid & 7) * 16; \
        const int p = (JC) * 64 + jl; \
        const int j = idx_s[p]; \
        const float* xj = x + (b * NN + j) * 3; \
        const float dx = xi0 - xj[0], dy = xi1 - xj[1], dz = xi2 - xj[2]; \
        const float d2 = dx * dx + dy * dy + dz * dz + 1e-8f; \
        const float* bp = Bpre + (size_t)(b * NN + j) * HD + h0; \
        char* dst = (char*)t1; \
        _Pragma("unroll") \
        for (int u = 0; u < 16; u += 8) { \
            const float4 bv0 = *(const float4*)(bp + u); \
            const float4 bv1 = *(const float4*)(bp + u + 4); \
            const float4 av0 = *(const float4*)(&Ai_s[h0 + u]); \
            const float4 av1 = *(const float4*)(&Ai_s[h0 + u + 4]); \
            const float4 wl0 = *(const float4*)(&wlast_s[h0 + u]); \
            const float4 wl1 = *(const float4*)(&wlast_s[h0 + u + 4]); \
            uint4 o; \
            o.x = pk2(fsilu(av0.x + bv0.x + d2 * wl0.x), fsilu(av0.y + bv0.y + d2 * wl0.y)); \
            o.y = pk2(fsilu(av0.z + bv0.z + d2 * wl0.z), fsilu(av0.w + bv0.w + d2 * wl0.w)); \
            o.z = pk2(fsilu(av1.x + bv1.x + d2 * wl1.x), fsilu(av1.y + bv1.y + d2 * wl1.y)); \
            o.w = pk2(fsilu(av1.z + bv1.z + d2 * wl1.z), fsilu(av1.w + bv1.w + d2 * wl1.w)); \
            *(uint4*)(dst + swz(jl, 2 * (h0 + u))) = o; \
        } \
    } while (0)

    if (nch > 0) PHASE_A(0);
    __syncthreads();

    for (int c = 0; c < nch; ++c) {
        const int j0 = c * 64;
        // ---- GEMM1: t2acc = m1 @ we2 (wave's 16 cols) ----
        f32x4 acc[4] = {zero4, zero4, zero4, zero4};
        #pragma unroll
        for (int ks = 0; ks < 4; ++ks) {
            #pragma unroll
            for (int mt = 0; mt < 4; ++mt) {
                const short8 a = *(const short8*)((char*)t1 + swz(mt * 16 + cl, ks * 64 + g * 16));
                acc[mt] = __builtin_amdgcn_mfma_f32_16x16x32_bf16(a, bw2[ks], acc[mt], 0, 0, 0);
            }
        }
        // ---- epilogue 1: m_ij = silu(+be2), pad rows zeroed -> t2; agg partials ----
        {
            const float bias = be2_s[mycol];
            #pragma unroll
            for (int mt = 0; mt < 4; ++mt) {
                #pragma unroll
                for (int r = 0; r < 4; ++r) {
                    const int jl = mt * 16 + g * 4 + r;
                    const float mp = (j0 + jl < cnt) ? 1.f : 0.f;
                    const float v = fsilu(acc[mt][r] + bias) * mp;
                    agg0 += v;
                    *(unsigned short*)((char*)t2 + swz(jl, 2 * mycol)) = us(v);
                }
            }
        }
        __syncthreads();
        // ---- overlap: next chunk's phase A hides under GEMM2 ----
        if (c + 1 < nch) PHASE_A(c + 1);
        // ---- GEMM2: t3acc = m_ij @ wc1 ----
        f32x4 acc2[4] = {zero4, zero4, zero4, zero4};
        #pragma unroll
        for (int ks = 0; ks < 4; ++ks) {
            #pragma unroll
            for (int mt = 0; mt < 4; ++mt) {
                const short8 a = *(const short8*)((char*)t2 + swz(mt * 16 + cl, ks * 64 + g * 16));
                acc2[mt] = __builtin_amdgcn_mfma_f32_16x16x32_bf16(a, bwc[ks], acc2[mt], 0, 0, 0);
            }
        }
        // ---- epilogue 2: sws partials = sum over wave's cols of silu(+bc1)*wc2 ----
        {
            const float bias = bc1_s[mycol];
            const float w2 = wc2_s[mycol];
            #pragma unroll
            for (int mt = 0; mt < 4; ++mt) {
                float sp0 = fsilu(acc2[mt][0] + bias) * w2;
                float sp1 = fsilu(acc2[mt][1] + bias) * w2;
                float sp2 = fsilu(acc2[mt][2] + bias) * w2;
                float sp3 = fsilu(acc2[mt][3] + bias) * w2;
                #pragma unroll
                for (int m = 1; m <= 8; m <<= 1) {
                    sp0 += __shfl_xor(sp0, m); sp1 += __shfl_xor(sp1, m);
                    sp2 += __shfl_xor(sp2, m); sp3 += __shfl_xor(sp3, m);
                }
                if (cl == 0) {
                    const int jb = mt * 16 + g * 4;
                    sws[wv][jb + 0] = sp0; sws[wv][jb + 1] = sp1;
                    sws[wv][jb + 2] = sp2; sws[wv][jb + 3] = sp3;
                }
            }
        }
        __syncthreads();
        // ---- finalize w_ij for this chunk, accumulate coords (wave 0) ----
        if (tid < 64) {
            const int p = j0 + tid;
            float s = sws[0][tid];
            #pragma unroll
            for (int w = 1; w < 8; ++w) s += sws[w][tid];
            const float w = ftanh(s) * 0.1f * ((p < cnt) ? 1.f : 0.f);
            const int j = idx_s[p];
            const float* xj = x + (b * NN + j) * 3;
            cdx += (xi0 - xj[0]) * w;
            cdy += (xi1 - xj[1]) * w;
            cdz += (xi2 - xj[2]) * w;
        }
    }
    #undef PHASE_A

    // agg: reduce over g-groups (rows), lane cl holds wave's col
    agg0 += __shfl_xor(agg0, 16); agg0 += __shfl_xor(agg0, 32);
    if (lane < 16) aggws[(size_t)rowb * HD + wv * 16 + lane] = agg0;
    // coords: wave-0 reduce + store
    if (tid < 64) {
        #pragma unroll
        for (int m = 1; m <= 32; m <<= 1) {
            cdx += __shfl_xor(cdx, m);
            cdy += __shfl_xor(cdy, m);
            cdz += __shfl_xor(cdz, m);
        }
        if (tid == 0) {
            xout[rowb * 3 + 0] = xi0 + cdx * (1.f / 256.f);
            xout[rowb * 3 + 1] = xi1 + cdy * (1.f / 256.f);
            xout[rowb * 3 + 2] = xi2 + cdz * (1.f / 256.f);
        }
    }
}

// ---- node MLP + LayerNorm: 16 rows per block, MFMA ----
__global__ __launch_bounds__(256) void node_mlp(
    const float* __restrict__ h, const float* __restrict__ aggws,
    const unsigned short* __restrict__ wn1pk, const unsigned short* __restrict__ wn2pk,
    const float* __restrict__ bn1, const float* __restrict__ bn2,
    const float* __restrict__ gamma, const float* __restrict__ beta,
    float* __restrict__ hout)
{
    const int r0 = blockIdx.x * 16;
    const int tid = threadIdx.x;
    const int wv = tid >> 6, lane = tid & 63, g = lane >> 4, cl = lane & 15;
    __shared__ __align__(16) unsigned short t1[16 * 256];
    __shared__ __align__(16) unsigned short t2[16 * HD];
    __shared__ float rs1[4][16], rs2[4][16];
    __shared__ float bn1_s[HD], bn2_s[HD], gam_s[HD], bet_s[HD];
    if (tid < HD) {
        bn1_s[tid] = bn1[tid]; bn2_s[tid] = bn2[tid];
        gam_s[tid] = gamma[tid]; bet_s[tid] = beta[tid];
    }
    {
        const int row = tid >> 4, k0 = (tid & 15) * 16;
        const float* src = (k0 < HD) ? (h + (size_t)(r0 + row) * HD + k0)
                                     : (aggws + (size_t)(r0 + row) * HD + (k0 - HD));
        char* dst = (char*)t1;
        #pragma unroll
        for (int u = 0; u < 16; u += 8) {
            const float4 a0 = *(const float4*)(src + u);
            const float4 a1 = *(const float4*)(src + u + 4);
            uint4 o;
            o.x = pk2(a0.x, a0.y); o.y = pk2(a0.z, a0.w);
            o.z = pk2(a1.x, a1.y); o.w = pk2(a1.z, a1.w);
            *(uint4*)(dst + swz512(row, 2 * (k0 + u))) = o;
        }
    }
    __syncthreads();
    const f32x4 zero4 = {0.f, 0.f, 0.f, 0.f};
    f32x4 acc[2] = {zero4, zero4};
    #pragma unroll
    for (int ks = 0; ks < 8; ++ks) {
        const short8 a = *(const short8*)((char*)t1 + swz512(cl, ks * 64 + g * 16));
        #pragma unroll
        for (int nt = 0; nt < 2; ++nt) {
            const int col = wv * 32 + nt * 16 + cl;
            const short8 bb = *(const short8*)(wn1pk + ((ks * 4 + g) * HD + col) * 8);
            acc[nt] = __builtin_amdgcn_mfma_f32_16x16x32_bf16(a, bb, acc[nt], 0, 0, 0);
        }
    }
    #pragma unroll
    for (int nt = 0; nt < 2; ++nt) {
        const int col = wv * 32 + nt * 16 + cl;
        const float bias = bn1_s[col];
        #pragma unroll
        for (int r = 0; r < 4; ++r) {
            const int row = g * 4 + r;
            *(unsigned short*)((char*)t2 + swz(row, 2 * col)) = us(fsilu(acc[nt][r] + bias));
        }
    }
    __syncthreads();
    f32x4 acc2[2] = {zero4, zero4};
    #pragma unroll
    for (int ks = 0; ks < 4; ++ks) {
        const short8 a = *(const short8*)((char*)t2 + swz(cl, ks * 64 + g * 16));
        #pragma unroll
        for (int nt = 0; nt < 2; ++nt) {
            const int col = wv * 32 + nt * 16 + cl;
            const short8 bb = *(const short8*)(wn2pk + ((ks * 4 + g) * HD + col) * 8);
            acc2[nt] = __builtin_amdgcn_mfma_f32_16x16x32_bf16(a, bb, acc2[nt], 0, 0, 0);
        }
    }
    float h2[2][4];
    #pragma unroll
    for (int nt = 0; nt < 2; ++nt) {
        const int col = wv * 32 + nt * 16 + cl;
        #pragma unroll
        for (int r = 0; r < 4; ++r) {
            const int row = g * 4 + r;
            h2[nt][r] = acc2[nt][r] + bn2_s[col] + h[(size_t)(r0 + row) * HD + col];
        }
    }
    #pragma unroll
    for (int r = 0; r < 4; ++r) {
        float p = h2[0][r] + h2[1][r];
        p += __shfl_xor(p, 1); p += __shfl_xor(p, 2);
        p += __shfl_xor(p, 4); p += __shfl_xor(p, 8);
        if (cl == 0) rs1[wv][g * 4 + r] = p;
    }
    __syncthreads();
    float mean[4];
    #pragma unroll
    for (int r = 0; r < 4; ++r) {
        const int row = g * 4 + r;
        mean[r] = (rs1[0][row] + rs1[1][row] + rs1[2][row] + rs1[3][row]) * (1.f / HD);
    }
    #pragma unroll
    for (int r = 0; r < 4; ++r) {
        const float d0 = h2[0][r] - mean[r], d1 = h2[1][r] - mean[r];
        float q = d0 * d0 + d1 * d1;
        q += __shfl_xor(q, 1); q += __shfl_xor(q, 2);
        q += __shfl_xor(q, 4); q += __shfl_xor(q, 8);
        if (cl == 0) rs2[wv][g * 4 + r] = q;
    }
    __syncthreads();
    #pragma unroll
    for (int r = 0; r < 4; ++r) {
        const int row = g * 4 + r;
        const float var = (rs2[0][row] + rs2[1][row] + rs2[2][row] + rs2[3][row]) * (1.f / HD);
        const float rsq = rsqrtf(var + 1e-5f);
        #pragma unroll
        for (int nt = 0; nt < 2; ++nt) {
            const int col = wv * 32 + nt * 16 + cl;
            hout[(size_t)(r0 + row) * HD + col] = (h2[nt][r] - mean[r]) * rsq * gam_s[col] + bet_s[col];
        }
    }
}

extern "C" void kernel_launch(void* const* d_in, const int* in_sizes, int n_in,
                              void* d_out, int out_size, void* d_ws, size_t ws_size,
                              hipStream_t stream)
{
    (void)in_sizes; (void)n_in; (void)out_size; (void)ws_size;
    const float* h     = (const float*)d_in[0];
    const float* x     = (const float*)d_in[1];
    const int*   mask  = (const int*)d_in[2];
    const float* we1   = (const float*)d_in[3];
    const float* be1   = (const float*)d_in[4];
    const float* we2   = (const float*)d_in[5];
    const float* be2   = (const float*)d_in[6];
    const float* wn1   = (const float*)d_in[7];
    const float* bn1   = (const float*)d_in[8];
    const float* wn2   = (const float*)d_in[9];
    const float* bn2   = (const float*)d_in[10];
    const float* wc1   = (const float*)d_in[11];
    const float* bc1   = (const float*)d_in[12];
    const float* wc2   = (const float*)d_in[13];
    const float* gamma = (const float*)d_in[14];
    const float* beta  = (const float*)d_in[15];

    float* out  = (float*)d_out;
    float* hout = out;
    float* xout = out + 8 * 256 * 128;

    float* Apre  = (float*)d_ws;
    float* Bpre  = Apre + 2048 * 128;
    float* aggws = Bpre + 2048 * 128;
    // we1pk aliases aggws: we1pk is dead before egcl_main writes aggws
    unsigned short* we1pk = (unsigned short*)aggws;
    unsigned short* we2pk = (unsigned short*)(aggws + 2048 * 128);
    unsigned short* wc1pk = we2pk + 128 * 128;
    unsigned short* wn1pk = wc1pk + 128 * 128;
    unsigned short* wn2pk = wn1pk + 256 * 128;
    int* idxB = (int*)(wn2pk + 128 * 128);
    int* cntB = idxB + 8 * 256;

    prep_all<<<456, 256, 0, stream>>>(we2, wc1, wn1, wn2, we1, mask,
                                      we2pk, wc1pk, wn1pk, wn2pk, we1pk, idxB, cntB);
    prep_node_mfma<<<128, 256, 0, stream>>>(h, we1pk, be1, Apre, Bpre);
    egcl_main<<<2048, 512, 0, stream>>>(x, mask, we1, be2, bc1, wc2,
                                        Apre, Bpre, we2pk, wc1pk, idxB, cntB,
                                        aggws, xout);
    node_mlp<<<128, 256, 0, stream>>>(h, aggws, wn1pk, wn2pk, bn1, bn2, gamma, beta, hout);
}

// Round 5
// 94.409 us; speedup vs baseline: 1.2121x; 1.2121x over previous
//
#include <hip/hip_runtime.h>
#include <hip/hip_bf16.h>

using short8 = __attribute__((ext_vector_type(8))) short;
using f32x4  = __attribute__((ext_vector_type(4))) float;

#define HD 128
#define NN 256

static __device__ __forceinline__ unsigned short us(float v) {
    union { __hip_bfloat16 b; unsigned short s; } c; c.b = __float2bfloat16(v); return c.s;
}
static __device__ __forceinline__ unsigned int pk2(float a, float b) {
    return (unsigned int)us(a) | ((unsigned int)us(b) << 16);
}
static __device__ __forceinline__ float fsilu(float v) {
    return __fdividef(v, 1.f + __expf(-v));
}
static __device__ __forceinline__ float ftanh(float v) {
    return 1.f - __fdividef(2.f, __expf(2.f * v) + 1.f);
}
// XOR-swizzled LDS byte addr for [rows][128] bf16 tile (256B row stride)
static __device__ __forceinline__ int swz(int row, int kbyte) { return row * 256 + (kbyte ^ ((row & 7) << 4)); }
// XOR-swizzled LDS byte addr for [rows][256] bf16 tile (512B row stride)
static __device__ __forceinline__ int swz512(int row, int kbyte) { return row * 512 + (kbyte ^ ((row & 7) << 4)); }

// ---- fused prep: weight packing (5 matrices) + mask compaction (full permutation) ----
__global__ __launch_bounds__(256) void prep_all(
    const float* __restrict__ we2, const float* __restrict__ wc1,
    const float* __restrict__ wn1, const float* __restrict__ wn2,
    const float* __restrict__ we1, const int* __restrict__ mask,
    unsigned short* __restrict__ we2pk, unsigned short* __restrict__ wc1pk,
    unsigned short* __restrict__ wn1pk, unsigned short* __restrict__ wn2pk,
    unsigned short* __restrict__ we1pk,
    int* __restrict__ idxB, int* __restrict__ cntB)
{
    const int blk = blockIdx.x;
    const int t = threadIdx.x;
    if (blk < 448) {
        const int idx = blk * 256 + t;          // 0..114687
        if (idx < 81920) {
            const float* src; unsigned short* dst; int local;
            if (idx < 16384)      { src = we2; dst = we2pk; local = idx;         }
            else if (idx < 32768) { src = wc1; dst = wc1pk; local = idx - 16384; }
            else if (idx < 65536) { src = wn1; dst = wn1pk; local = idx - 32768; }
            else                  { src = wn2; dst = wn2pk; local = idx - 65536; }
            const int k = local >> 7, n = local & 127;
            dst[((k >> 3) * 128 + n) * 8 + (k & 7)] = us(src[local]);
        } else {
            // we1 combined: W[k][n] = (n<128) ? we1[k][n] : we1[128+k][n-128]
            const int local = idx - 81920;      // 0..32767
            const int k = local >> 8, n = local & 255;
            const int srci = (n < HD) ? (k * HD + n) : ((HD + k) * HD + (n - HD));
            we1pk[((k >> 3) * 256 + n) * 8 + (k & 7)] = us(we1[srci]);
        }
    } else {
        // mask compaction: actives at [0,cnt), inactives at [cnt,256)
        const int b = blk - 448;                // 0..7
        const int lane = t & 63, wvp = t >> 6;
        const int m = mask[b * NN + t];
        const unsigned long long bal = __ballot(m != 0);
        const int pos = __popcll(bal & ((1ULL << lane) - 1ULL));
        __shared__ int wc[4];
        if (lane == 0) wc[wvp] = __popcll(bal);
        __syncthreads();
        int base = 0;
        for (int w = 0; w < wvp; ++w) base += wc[w];
        const int cnt = wc[0] + wc[1] + wc[2] + wc[3];
        const int act_before = base + pos;
        const int slot = m ? act_before : cnt + (t - act_before);
        idxB[b * NN + slot] = t;
        if (t == 0) cntB[b] = cnt;
    }
}

// ---- prep: Apre/Bpre = h @ W (256 cols) via MFMA (16 rows/block) ----
__global__ __launch_bounds__(256) void prep_node_mfma(
    const float* __restrict__ h, const unsigned short* __restrict__ we1pk,
    const float* __restrict__ be1,
    float* __restrict__ Apre, float* __restrict__ Bpre)
{
    const int r0 = blockIdx.x * 16;
    const int tid = threadIdx.x;
    const int wv = tid >> 6, lane = tid & 63, g = lane >> 4, cl = lane & 15;
    __shared__ __align__(16) unsigned short t1[16 * HD];
    {
        const int row = tid >> 4, k0 = (tid & 15) * 8;
        const float4 a0 = *(const float4*)(h + (size_t)(r0 + row) * HD + k0);
        const float4 a1 = *(const float4*)(h + (size_t)(r0 + row) * HD + k0 + 4);
        uint4 o;
        o.x = pk2(a0.x, a0.y); o.y = pk2(a0.z, a0.w);
        o.z = pk2(a1.x, a1.y); o.w = pk2(a1.z, a1.w);
        *(uint4*)((char*)t1 + swz(row, 2 * k0)) = o;
    }
    __syncthreads();
    const f32x4 zero4 = {0.f, 0.f, 0.f, 0.f};
    f32x4 acc[4] = {zero4, zero4, zero4, zero4};
    #pragma unroll
    for (int ks = 0; ks < 4; ++ks) {
        const short8 a = *(const short8*)((char*)t1 + swz(cl, ks * 64 + g * 16));
        #pragma unroll
        for (int nt = 0; nt < 4; ++nt) {
            const int col = wv * 64 + nt * 16 + cl;
            const short8 bb = *(const short8*)(we1pk + ((ks * 4 + g) * 256 + col) * 8);
            acc[nt] = __builtin_amdgcn_mfma_f32_16x16x32_bf16(a, bb, acc[nt], 0, 0, 0);
        }
    }
    #pragma unroll
    for (int nt = 0; nt < 4; ++nt) {
        const int col = wv * 64 + nt * 16 + cl;
        const float bias = (col < HD) ? be1[col] : 0.f;
        #pragma unroll
        for (int r = 0; r < 4; ++r) {
            const int row = r0 + g * 4 + r;
            const float v = acc[nt][r] + bias;
            if (col < HD) Apre[(size_t)row * HD + col] = v;
            else          Bpre[(size_t)row * HD + (col - HD)] = v;
        }
    }
}

// ---- main: one 128-thread block (2 waves) per node; active nodes do edge MLPs ----
// Wave wv owns output cols [wv*64, wv*64+64) and phase-A K-half [wv*64, wv*64+64).
__global__ __launch_bounds__(128) void egcl_main(
    const float* __restrict__ x, const float* __restrict__ we1,
    const float* __restrict__ be2, const float* __restrict__ bc1,
    const float* __restrict__ wc2,
    const float* __restrict__ Apre, const float* __restrict__ Bpre,
    const unsigned short* __restrict__ we2pk, const unsigned short* __restrict__ wc1pk,
    const int* __restrict__ idxB, const int* __restrict__ cntB,
    float* __restrict__ aggws, float* __restrict__ xout)
{
    const int blk = blockIdx.x;
    const int b = blk >> 8, p = blk & 255;
    const int tid = threadIdx.x;
    const int wv = tid >> 6, lane = tid & 63, g = lane >> 4, cl = lane & 15;

    const int cnt = cntB[b];
    const int i = idxB[b * NN + p];          // full permutation: [actives | inactives]
    const int rowb = b * NN + i;

    if (p >= cnt) {                          // inactive node: zero agg, copy x
        aggws[(size_t)rowb * HD + tid] = 0.f;
        if (tid < 3) xout[rowb * 3 + tid] = x[rowb * 3 + tid];
        return;
    }

    __shared__ __align__(16) unsigned short m1[16 * HD];
    __shared__ __align__(16) unsigned short t2[16 * HD];
    __shared__ float sws[2][16];
    __shared__ float cdp[2][3];

    // per-wave weight fragments (cols wv*64 .. wv*64+63)
    short8 bw2[4][4], bwc[4][4];
    #pragma unroll
    for (int ks = 0; ks < 4; ++ks) {
        #pragma unroll
        for (int n = 0; n < 4; ++n) {
            const int off = ((ks * 4 + g) * HD + wv * 64 + n * 16 + cl) * 8;
            bw2[ks][n] = *(const short8*)(we2pk + off);
            bwc[ks][n] = *(const short8*)(wc1pk + off);
        }
    }
    float be2v[4], bc1v[4], wc2v[4];
    #pragma unroll
    for (int n = 0; n < 4; ++n) {
        const int col = wv * 64 + n * 16 + cl;
        be2v[n] = be2[col]; bc1v[n] = bc1[col]; wc2v[n] = wc2[col];
    }

    const float xi0 = x[rowb * 3 + 0];
    const float xi1 = x[rowb * 3 + 1];
    const float xi2 = x[rowb * 3 + 2];
    float agg[4] = {0.f, 0.f, 0.f, 0.f};
    float cdx = 0.f, cdy = 0.f, cdz = 0.f;
    const f32x4 zero4 = {0.f, 0.f, 0.f, 0.f};
    const int nch = (cnt + 15) >> 4;

    // phase A for chunk C: wave computes its K-half of m1[16 rows][128]
    #define PHASE_A(C) do { \
        const int pj = (C) * 16 + cl; \
        const int j = idxB[b * NN + pj]; \
        const float* xj = x + (b * NN + j) * 3; \
        const float dx = xi0 - xj[0], dy = xi1 - xj[1], dz = xi2 - xj[2]; \
        const float d2 = dx * dx + dy * dy + dz * dz + 1e-8f; \
        _Pragma("unroll") \
        for (int kk = 0; kk < 2; ++kk) { \
            const int ks = wv * 2 + kk; \
            const int k0 = g * 8 + ks * 32; \
            const float4 b0 = *(const float4*)(Bpre + (size_t)(b * NN + j) * HD + k0); \
            const float4 b1 = *(const float4*)(Bpre + (size_t)(b * NN + j) * HD + k0 + 4); \
            const float4 a0 = *(const float4*)(Apre + (size_t)rowb * HD + k0); \
            const float4 a1 = *(const float4*)(Apre + (size_t)rowb * HD + k0 + 4); \
            const float4 w0 = *(const float4*)(we1 + 2 * HD * HD + k0); \
            const float4 w1 = *(const float4*)(we1 + 2 * HD * HD + k0 + 4); \
            uint4 o; \
            o.x = pk2(fsilu(a0.x + b0.x + d2 * w0.x), fsilu(a0.y + b0.y + d2 * w0.y)); \
            o.y = pk2(fsilu(a0.z + b0.z + d2 * w0.z), fsilu(a0.w + b0.w + d2 * w0.w)); \
            o.z = pk2(fsilu(a1.x + b1.x + d2 * w1.x), fsilu(a1.y + b1.y + d2 * w1.y)); \
            o.w = pk2(fsilu(a1.z + b1.z + d2 * w1.z), fsilu(a1.w + b1.w + d2 * w1.w)); \
            *(uint4*)((char*)m1 + swz(cl, 2 * k0)) = o; \
        } \
    } while (0)

    // w_ij finalize for chunk C: rows split across waves (wave wv -> rows wv*8..wv*8+7)
    #define FINALIZE(C) do { \
        if (lane < 8) { \
            const int row = wv * 8 + lane; \
            const int pj = (C) * 16 + row; \
            if (pj < cnt) { \
                const float s = sws[0][row] + sws[1][row]; \
                const int j = idxB[b * NN + pj]; \
                const float w = ftanh(s) * 0.1f; \
                const float* xj = x + (b * NN + j) * 3; \
                cdx += (xi0 - xj[0]) * w; \
                cdy += (xi1 - xj[1]) * w; \
                cdz += (xi2 - xj[2]) * w; \
            } \
        } \
    } while (0)

    PHASE_A(0);
    __syncthreads();

    for (int c = 0; c < nch; ++c) {
        if (c > 0) FINALIZE(c - 1);
        // ---- GEMM1: acc = m1 @ we2 (wave's 64 cols) ----
        f32x4 acc[4] = {zero4, zero4, zero4, zero4};
        #pragma unroll
        for (int ks = 0; ks < 4; ++ks) {
            const short8 a = *(const short8*)((char*)m1 + swz(cl, 2 * (g * 8 + ks * 32)));
            #pragma unroll
            for (int n = 0; n < 4; ++n)
                acc[n] = __builtin_amdgcn_mfma_f32_16x16x32_bf16(a, bw2[ks][n], acc[n], 0, 0, 0);
        }
        // ---- epilogue 1: m_ij = silu(+be2) (pads zeroed) -> t2; agg partials ----
        #pragma unroll
        for (int n = 0; n < 4; ++n) {
            const int col = wv * 64 + n * 16 + cl;
            #pragma unroll
            for (int r = 0; r < 4; ++r) {
                const int row = g * 4 + r;
                const float mp = (c * 16 + row < cnt) ? 1.f : 0.f;
                const float v = fsilu(acc[n][r] + be2v[n]) * mp;
                agg[n] += v;
                *(unsigned short*)((char*)t2 + swz(row, 2 * col)) = us(v);
            }
        }
        __syncthreads();
        // ---- GEMM2: acc2 = m_ij @ wc1 ----
        f32x4 acc2[4] = {zero4, zero4, zero4, zero4};
        #pragma unroll
        for (int ks = 0; ks < 4; ++ks) {
            const short8 a2 = *(const short8*)((char*)t2 + swz(cl, 2 * (g * 8 + ks * 32)));
            #pragma unroll
            for (int n = 0; n < 4; ++n)
                acc2[n] = __builtin_amdgcn_mfma_f32_16x16x32_bf16(a2, bwc[ks][n], acc2[n], 0, 0, 0);
        }
        // ---- epilogue 2: per-row partial over wave's 64 cols -> sws ----
        #pragma unroll
        for (int r = 0; r < 4; ++r) {
            float sr = 0.f;
            #pragma unroll
            for (int n = 0; n < 4; ++n) sr += fsilu(acc2[n][r] + bc1v[n]) * wc2v[n];
            sr += __shfl_xor(sr, 1); sr += __shfl_xor(sr, 2);
            sr += __shfl_xor(sr, 4); sr += __shfl_xor(sr, 8);
            if (cl == 0) sws[wv][g * 4 + r] = sr;
        }
        // ---- next chunk's phase A overlaps this segment ----
        if (c + 1 < nch) PHASE_A(c + 1);
        __syncthreads();
    }
    FINALIZE(nch - 1);
    #undef PHASE_A
    #undef FINALIZE

    // agg: reduce over row-groups; lanes 0..15 hold col totals
    #pragma unroll
    for (int n = 0; n < 4; ++n) {
        agg[n] += __shfl_xor(agg[n], 16);
        agg[n] += __shfl_xor(agg[n], 32);
    }
    if (lane < 16) {
        #pragma unroll
        for (int n = 0; n < 4; ++n)
            aggws[(size_t)rowb * HD + wv * 64 + n * 16 + lane] = agg[n];
    }
    // coords: reduce lanes 0..7 within wave, combine across waves
    cdx += __shfl_xor(cdx, 1); cdx += __shfl_xor(cdx, 2); cdx += __shfl_xor(cdx, 4);
    cdy += __shfl_xor(cdy, 1); cdy += __shfl_xor(cdy, 2); cdy += __shfl_xor(cdy, 4);
    cdz += __shfl_xor(cdz, 1); cdz += __shfl_xor(cdz, 2); cdz += __shfl_xor(cdz, 4);
    if (lane == 0) { cdp[wv][0] = cdx; cdp[wv][1] = cdy; cdp[wv][2] = cdz; }
    __syncthreads();
    if (tid == 0) {
        xout[rowb * 3 + 0] = xi0 + (cdp[0][0] + cdp[1][0]) * (1.f / 256.f);
        xout[rowb * 3 + 1] = xi1 + (cdp[0][1] + cdp[1][1]) * (1.f / 256.f);
        xout[rowb * 3 + 2] = xi2 + (cdp[0][2] + cdp[1][2]) * (1.f / 256.f);
    }
}

// ---- node MLP + LayerNorm: 16 rows per block, MFMA ----
__global__ __launch_bounds__(256) void node_mlp(
    const float* __restrict__ h, const float* __restrict__ aggws,
    const unsigned short* __restrict__ wn1pk, const unsigned short* __restrict__ wn2pk,
    const float* __restrict__ bn1, const float* __restrict__ bn2,
    const float* __restrict__ gamma, const float* __restrict__ beta,
    float* __restrict__ hout)
{
    const int r0 = blockIdx.x * 16;
    const int tid = threadIdx.x;
    const int wv = tid >> 6, lane = tid & 63, g = lane >> 4, cl = lane & 15;
    __shared__ __align__(16) unsigned short t1[16 * 256];
    __shared__ __align__(16) unsigned short t2[16 * HD];
    __shared__ float rs1[4][16], rs2[4][16];
    __shared__ float bn1_s[HD], bn2_s[HD], gam_s[HD], bet_s[HD];
    if (tid < HD) {
        bn1_s[tid] = bn1[tid]; bn2_s[tid] = bn2[tid];
        gam_s[tid] = gamma[tid]; bet_s[tid] = beta[tid];
    }
    {
        const int row = tid >> 4, k0 = (tid & 15) * 16;
        const float* src = (k0 < HD) ? (h + (size_t)(r0 + row) * HD + k0)
                                     : (aggws + (size_t)(r0 + row) * HD + (k0 - HD));
        char* dst = (char*)t1;
        #pragma unroll
        for (int u = 0; u < 16; u += 8) {
            const float4 a0 = *(const float4*)(src + u);
            const float4 a1 = *(const float4*)(src + u + 4);
            uint4 o;
            o.x = pk2(a0.x, a0.y); o.y = pk2(a0.z, a0.w);
            o.z = pk2(a1.x, a1.y); o.w = pk2(a1.z, a1.w);
            *(uint4*)(dst + swz512(row, 2 * (k0 + u))) = o;
        }
    }
    __syncthreads();
    const f32x4 zero4 = {0.f, 0.f, 0.f, 0.f};
    f32x4 acc[2] = {zero4, zero4};
    #pragma unroll
    for (int ks = 0; ks < 8; ++ks) {
        const short8 a = *(const short8*)((char*)t1 + swz512(cl, ks * 64 + g * 16));
        #pragma unroll
        for (int nt = 0; nt < 2; ++nt) {
            const int col = wv * 32 + nt * 16 + cl;
            const short8 bb = *(const short8*)(wn1pk + ((ks * 4 + g) * HD + col) * 8);
            acc[nt] = __builtin_amdgcn_mfma_f32_16x16x32_bf16(a, bb, acc[nt], 0, 0, 0);
        }
    }
    #pragma unroll
    for (int nt = 0; nt < 2; ++nt) {
        const int col = wv * 32 + nt * 16 + cl;
        const float bias = bn1_s[col];
        #pragma unroll
        for (int r = 0; r < 4; ++r) {
            const int row = g * 4 + r;
            *(unsigned short*)((char*)t2 + swz(row, 2 * col)) = us(fsilu(acc[nt][r] + bias));
        }
    }
    __syncthreads();
    f32x4 acc2[2] = {zero4, zero4};
    #pragma unroll
    for (int ks = 0; ks < 4; ++ks) {
        const short8 a = *(const short8*)((char*)t2 + swz(cl, ks * 64 + g * 16));
        #pragma unroll
        for (int nt = 0; nt < 2; ++nt) {
            const int col = wv * 32 + nt * 16 + cl;
            const short8 bb = *(const short8*)(wn2pk + ((ks * 4 + g) * HD + col) * 8);
            acc2[nt] = __builtin_amdgcn_mfma_f32_16x16x32_bf16(a, bb, acc2[nt], 0, 0, 0);
        }
    }
    float h2[2][4];
    #pragma unroll
    for (int nt = 0; nt < 2; ++nt) {
        const int col = wv * 32 + nt * 16 + cl;
        #pragma unroll
        for (int r = 0; r < 4; ++r) {
            const int row = g * 4 + r;
            h2[nt][r] = acc2[nt][r] + bn2_s[col] + h[(size_t)(r0 + row) * HD + col];
        }
    }
    #pragma unroll
    for (int r = 0; r < 4; ++r) {
        float pp = h2[0][r] + h2[1][r];
        pp += __shfl_xor(pp, 1); pp += __shfl_xor(pp, 2);
        pp += __shfl_xor(pp, 4); pp += __shfl_xor(pp, 8);
        if (cl == 0) rs1[wv][g * 4 + r] = pp;
    }
    __syncthreads();
    float mean[4];
    #pragma unroll
    for (int r = 0; r < 4; ++r) {
        const int row = g * 4 + r;
        mean[r] = (rs1[0][row] + rs1[1][row] + rs1[2][row] + rs1[3][row]) * (1.f / HD);
    }
    #pragma unroll
    for (int r = 0; r < 4; ++r) {
        const float d0 = h2[0][r] - mean[r], d1 = h2[1][r] - mean[r];
        float q = d0 * d0 + d1 * d1;
        q += __shfl_xor(q, 1); q += __shfl_xor(q, 2);
        q += __shfl_xor(q, 4); q += __shfl_xor(q, 8);
        if (cl == 0) rs2[wv][g * 4 + r] = q;
    }
    __syncthreads();
    #pragma unroll
    for (int r = 0; r < 4; ++r) {
        const int row = g * 4 + r;
        const float var = (rs2[0][row] + rs2[1][row] + rs2[2][row] + rs2[3][row]) * (1.f / HD);
        const float rsq = rsqrtf(var + 1e-5f);
        #pragma unroll
        for (int nt = 0; nt < 2; ++nt) {
            const int col = wv * 32 + nt * 16 + cl;
            hout[(size_t)(r0 + row) * HD + col] = (h2[nt][r] - mean[r]) * rsq * gam_s[col] + bet_s[col];
        }
    }
}

extern "C" void kernel_launch(void* const* d_in, const int* in_sizes, int n_in,
                              void* d_out, int out_size, void* d_ws, size_t ws_size,
                              hipStream_t stream)
{
    (void)in_sizes; (void)n_in; (void)out_size; (void)ws_size;
    const float* h     = (const float*)d_in[0];
    const float* x     = (const float*)d_in[1];
    const int*   mask  = (const int*)d_in[2];
    const float* we1   = (const float*)d_in[3];
    const float* be1   = (const float*)d_in[4];
    const float* we2   = (const float*)d_in[5];
    const float* be2   = (const float*)d_in[6];
    const float* wn1   = (const float*)d_in[7];
    const float* bn1   = (const float*)d_in[8];
    const float* wn2   = (const float*)d_in[9];
    const float* bn2   = (const float*)d_in[10];
    const float* wc1   = (const float*)d_in[11];
    const float* bc1   = (const float*)d_in[12];
    const float* wc2   = (const float*)d_in[13];
    const float* gamma = (const float*)d_in[14];
    const float* beta  = (const float*)d_in[15];

    float* out  = (float*)d_out;
    float* hout = out;
    float* xout = out + 8 * 256 * 128;

    float* Apre  = (float*)d_ws;
    float* Bpre  = Apre + 2048 * 128;
    float* aggws = Bpre + 2048 * 128;
    // we1pk aliases aggws: we1pk is dead before egcl_main writes aggws
    unsigned short* we1pk = (unsigned short*)aggws;
    unsigned short* we2pk = (unsigned short*)(aggws + 2048 * 128);
    unsigned short* wc1pk = we2pk + 128 * 128;
    unsigned short* wn1pk = wc1pk + 128 * 128;
    unsigned short* wn2pk = wn1pk + 256 * 128;
    int* idxB = (int*)(wn2pk + 128 * 128);
    int* cntB = idxB + 8 * 256;

    prep_all<<<456, 256, 0, stream>>>(we2, wc1, wn1, wn2, we1, mask,
                                      we2pk, wc1pk, wn1pk, wn2pk, we1pk, idxB, cntB);
    prep_node_mfma<<<128, 256, 0, stream>>>(h, we1pk, be1, Apre, Bpre);
    egcl_main<<<2048, 128, 0, stream>>>(x, we1, be2, bc1, wc2,
                                        Apre, Bpre, we2pk, wc1pk, idxB, cntB,
                                        aggws, xout);
    node_mlp<<<128, 256, 0, stream>>>(h, aggws, wn1pk, wn2pk, bn1, bn2, gamma, beta, hout);
}